// Round 1
// baseline (559.658 us; speedup 1.0000x reference)
//
#include <hip/hip_runtime.h>
#include <hip/hip_bf16.h>
#include <cstdint>

typedef __attribute__((ext_vector_type(8))) short bf16x8;   // 8 bf16 = 4 VGPRs
typedef __attribute__((ext_vector_type(4))) float f32x4;

static constexpr int Mdim = 8192;
static constexpr int Kdim = 4096;
static constexpr int Ndim = 4096;
static constexpr int BM = 128, BN = 128, BK = 32;

__device__ __forceinline__ void async_copy16(const void* g, void* l) {
  __builtin_amdgcn_global_load_lds(
      (const __attribute__((address_space(1))) void*)g,
      (__attribute__((address_space(3))) void*)l, 16, 0, 0);
}

// ---- prepass 1: x fp32 -> bf16 (8 elems/thread, 16B stores) ----
__global__ __launch_bounds__(256) void cvt_x_kernel(const float* __restrict__ x,
                                                    __hip_bfloat16* __restrict__ xb) {
  size_t base = ((size_t)blockIdx.x * 256 + threadIdx.x) * 8;
  const float4* p = reinterpret_cast<const float4*>(x + base);
  float4 v0 = p[0], v1 = p[1];
  float vals[8] = {v0.x, v0.y, v0.z, v0.w, v1.x, v1.y, v1.z, v1.w};
  union { __hip_bfloat16 h[8]; uint4 u; } o;
  #pragma unroll
  for (int j = 0; j < 8; ++j) o.h[j] = __float2bfloat16(vals[j]);
  *reinterpret_cast<uint4*>(xb + base) = o.u;
}

// ---- prepass 2: w [K][N] fp32 -> bwT [N][K] bf16 holding sign(w) ----
__global__ __launch_bounds__(256) void bin_w_kernel(const float* __restrict__ w,
                                                    __hip_bfloat16* __restrict__ bwT) {
  __shared__ __hip_bfloat16 tile[64][65];   // +1 pad breaks transpose conflicts
  int k0 = blockIdx.x * 64;
  int n0 = blockIdx.y * 64;
  int tx = threadIdx.x & 63;
  int ty = threadIdx.x >> 6;
  #pragma unroll
  for (int i = 0; i < 16; ++i) {
    int k = ty + 4 * i;
    float v = w[(size_t)(k0 + k) * Ndim + n0 + tx];
    float s = (v > 0.f) ? 1.f : ((v < 0.f) ? -1.f : 0.f);  // jnp.sign semantics
    tile[k][tx] = __float2bfloat16(s);
  }
  __syncthreads();
  #pragma unroll
  for (int i = 0; i < 16; ++i) {
    int n = ty + 4 * i;
    bwT[(size_t)(n0 + n) * Kdim + k0 + tx] = tile[tx][n];
  }
}

// ---- main GEMM (m97 structure): A [M][K] bf16, Bt [N][K] bf16, out fp32 ----
__global__ __launch_bounds__(256) void gemm_kernel(const __hip_bfloat16* __restrict__ A,
                                                   const __hip_bfloat16* __restrict__ Bt,
                                                   const float* __restrict__ bias,
                                                   float* __restrict__ out) {
  __shared__ __hip_bfloat16 sA[BM * BK];   // [128][32], linear (global_load_lds: no pad)
  __shared__ __hip_bfloat16 sB[BN * BK];   // [128][32] of B^T
  const int tid  = threadIdx.x;
  const int bn   = blockIdx.x, bm = blockIdx.y;
  const int lane = tid & 63;
  const int wave = tid >> 6;
  const int wm   = (wave & 1) * 64;    // wave sub-tile origin in M
  const int wn   = (wave >> 1) * 64;   // ... in N
  const int lr   = lane & 15;
  const int quad = lane >> 4;

  // staging chunk ids: 16B per thread per round, 2 rounds cover 128x32 bf16
  const int c0 = tid, c1 = tid + 256;
  const int rowA0 = c0 >> 2, colA0 = (c0 & 3) * 8;
  const int rowA1 = c1 >> 2, colA1 = (c1 & 3) * 8;
  const __hip_bfloat16* gA0 = A  + (size_t)(bm * BM + rowA0) * Kdim + colA0;
  const __hip_bfloat16* gA1 = A  + (size_t)(bm * BM + rowA1) * Kdim + colA1;
  const __hip_bfloat16* gB0 = Bt + (size_t)(bn * BN + rowA0) * Kdim + colA0;
  const __hip_bfloat16* gB1 = Bt + (size_t)(bn * BN + rowA1) * Kdim + colA1;

  f32x4 acc[4][4] = {};

  for (int k0 = 0; k0 < Kdim; k0 += BK) {
    async_copy16(gA0 + k0, &sA[c0 * 8]);
    async_copy16(gA1 + k0, &sA[c1 * 8]);
    async_copy16(gB0 + k0, &sB[c0 * 8]);
    async_copy16(gB1 + k0, &sB[c1 * 8]);
    __syncthreads();

    bf16x8 af[4], bf[4];
    #pragma unroll
    for (int i = 0; i < 4; ++i)
      af[i] = *reinterpret_cast<const bf16x8*>(&sA[(wm + i * 16 + lr) * BK + quad * 8]);
    #pragma unroll
    for (int j = 0; j < 4; ++j)
      bf[j] = *reinterpret_cast<const bf16x8*>(&sB[(wn + j * 16 + lr) * BK + quad * 8]);
    #pragma unroll
    for (int i = 0; i < 4; ++i)
      #pragma unroll
      for (int j = 0; j < 4; ++j)
        acc[i][j] = __builtin_amdgcn_mfma_f32_16x16x32_bf16(af[i], bf[j], acc[i][j], 0, 0, 0);
    __syncthreads();
  }

  // epilogue: C/D layout col=lane&15, row=quad*4+reg ; fuse bias
  float bv[4];
  #pragma unroll
  for (int j = 0; j < 4; ++j) bv[j] = bias[bn * BN + wn + j * 16 + lr];
  #pragma unroll
  for (int i = 0; i < 4; ++i) {
    const size_t rowb = (size_t)(bm * BM + wm + i * 16 + quad * 4);
    #pragma unroll
    for (int j = 0; j < 4; ++j) {
      const int col = bn * BN + wn + j * 16 + lr;
      float* o = out + rowb * Ndim + col;
      #pragma unroll
      for (int r = 0; r < 4; ++r)
        o[(size_t)r * Ndim] = acc[i][j][r] + bv[j];
    }
  }
}

// ---- fallback (no workspace): fused convert/binarize staging ----
__global__ __launch_bounds__(256) void gemm_fused_kernel(const float* __restrict__ X,
                                                         const float* __restrict__ W,
                                                         const float* __restrict__ bias,
                                                         float* __restrict__ out) {
  __shared__ __hip_bfloat16 sA[BM * BK];
  __shared__ __hip_bfloat16 sB[BN * BK];   // stored [n][k]
  const int tid  = threadIdx.x;
  const int bn   = blockIdx.x, bm = blockIdx.y;
  const int lane = tid & 63;
  const int wave = tid >> 6;
  const int wm   = (wave & 1) * 64;
  const int wn   = (wave >> 1) * 64;
  const int lr   = lane & 15;
  const int quad = lane >> 4;

  f32x4 acc[4][4] = {};

  for (int k0 = 0; k0 < Kdim; k0 += BK) {
    #pragma unroll
    for (int r = 0; r < 2; ++r) {
      int c = r * 256 + tid;
      // A: row-major chunks of 8
      int row = c >> 2, col = (c & 3) * 8;
      const float4* p = reinterpret_cast<const float4*>(X + (size_t)(bm * BM + row) * Kdim + k0 + col);
      float4 v0 = p[0], v1 = p[1];
      float va[8] = {v0.x, v0.y, v0.z, v0.w, v1.x, v1.y, v1.z, v1.w};
      union { __hip_bfloat16 h[8]; uint4 u; } oa;
      #pragma unroll
      for (int u2 = 0; u2 < 8; ++u2) oa.h[u2] = __float2bfloat16(va[u2]);
      *reinterpret_cast<uint4*>(&sA[c * 8]) = oa.u;

      // B: read w row (coalesced over n), binarize, transpose-scatter to sB[n][k]
      int kl = c >> 4, n8 = (c & 15) * 8;
      const float4* q = reinterpret_cast<const float4*>(W + (size_t)(k0 + kl) * Ndim + bn * BN + n8);
      float4 w0 = q[0], w1 = q[1];
      float wv[8] = {w0.x, w0.y, w0.z, w0.w, w1.x, w1.y, w1.z, w1.w};
      #pragma unroll
      for (int u2 = 0; u2 < 8; ++u2) {
        float s = (wv[u2] > 0.f) ? 1.f : ((wv[u2] < 0.f) ? -1.f : 0.f);
        sB[(n8 + u2) * BK + kl] = __float2bfloat16(s);
      }
    }
    __syncthreads();

    bf16x8 af[4], bf[4];
    #pragma unroll
    for (int i = 0; i < 4; ++i)
      af[i] = *reinterpret_cast<const bf16x8*>(&sA[(wm + i * 16 + lr) * BK + quad * 8]);
    #pragma unroll
    for (int j = 0; j < 4; ++j)
      bf[j] = *reinterpret_cast<const bf16x8*>(&sB[(wn + j * 16 + lr) * BK + quad * 8]);
    #pragma unroll
    for (int i = 0; i < 4; ++i)
      #pragma unroll
      for (int j = 0; j < 4; ++j)
        acc[i][j] = __builtin_amdgcn_mfma_f32_16x16x32_bf16(af[i], bf[j], acc[i][j], 0, 0, 0);
    __syncthreads();
  }

  float bv[4];
  #pragma unroll
  for (int j = 0; j < 4; ++j) bv[j] = bias[bn * BN + wn + j * 16 + lr];
  #pragma unroll
  for (int i = 0; i < 4; ++i) {
    const size_t rowb = (size_t)(bm * BM + wm + i * 16 + quad * 4);
    #pragma unroll
    for (int j = 0; j < 4; ++j) {
      const int col = bn * BN + wn + j * 16 + lr;
      float* o = out + rowb * Ndim + col;
      #pragma unroll
      for (int r = 0; r < 4; ++r)
        o[(size_t)r * Ndim] = acc[i][j][r] + bv[j];
    }
  }
}

extern "C" void kernel_launch(void* const* d_in, const int* in_sizes, int n_in,
                              void* d_out, int out_size, void* d_ws, size_t ws_size,
                              hipStream_t stream) {
  const float* x = (const float*)d_in[0];   // [8192,4096]
  const float* w = (const float*)d_in[1];   // [4096,4096]
  const float* b = (const float*)d_in[2];   // [4096]
  float* out = (float*)d_out;

  const size_t need = (size_t)Mdim * Kdim * 2 + (size_t)Ndim * Kdim * 2;  // 96 MiB
  if (ws_size >= need) {
    __hip_bfloat16* xb  = (__hip_bfloat16*)d_ws;
    __hip_bfloat16* bwT = (__hip_bfloat16*)((char*)d_ws + (size_t)Mdim * Kdim * 2);
    cvt_x_kernel<<<((size_t)Mdim * Kdim) / 2048, 256, 0, stream>>>(x, xb);
    bin_w_kernel<<<dim3(Kdim / 64, Ndim / 64), 256, 0, stream>>>(w, bwT);
    gemm_kernel<<<dim3(Ndim / BN, Mdim / BM), 256, 0, stream>>>(xb, bwT, b, out);
  } else {
    gemm_fused_kernel<<<dim3(Ndim / BN, Mdim / BM), 256, 0, stream>>>(x, w, b, out);
  }
}